// Round 2
// 991.223 us; speedup vs baseline: 1.7019x; 1.7019x over previous
//
#include <hip/hip_runtime.h>
#include <cstdint>
#include <cstddef>

#define NNODES 10000
#define HDIM 64
#define BDIM 2
#define INDIM 128
#define TSTEPS 50

__device__ __forceinline__ float sigmoidf_(float x){ return 1.0f/(1.0f+__expf(-x)); }
__device__ __forceinline__ float tanhf_(float x){ float e=__expf(2.0f*x); return 1.0f-2.0f/(e+1.0f); }

__device__ __forceinline__ uint32_t pack_bf16x2(float a, float b){
  uint32_t ua = __float_as_uint(a), ub = __float_as_uint(b);
  ua = (ua + 0x7fffu + ((ua>>16)&1u)) >> 16;          // rne
  ub = (ub + 0x7fffu + ((ub>>16)&1u)) >> 16;
  return ua | (ub<<16);
}

__global__ void hist_kernel(const int* __restrict__ src, const int* __restrict__ dst,
                            int* __restrict__ deg_out, int* __restrict__ deg_in, int E){
  int e = blockIdx.x*blockDim.x + threadIdx.x;
  if (e < E){
    atomicAdd(&deg_out[src[e]], 1);
    atomicAdd(&deg_in[dst[e]], 1);
  }
}

// row_off uses degrees PADDED to multiples of 8 (branch-free 8-unroll gather)
__global__ void scan_kernel(const int* __restrict__ deg_in, const int* __restrict__ deg_out,
                            int* __restrict__ row_off, int* __restrict__ cursor,
                            float* __restrict__ norm_s, float* __restrict__ norm_d){
  __shared__ int part[256];
  int tid = threadIdx.x;
  const int CH = (NNODES + 255)/256;   // 40
  int base = tid*CH;
  int local = 0;
  for (int k=0;k<CH;k++){ int n=base+k; if(n<NNODES) local += (deg_in[n]+7)&~7; }
  part[tid]=local;
  __syncthreads();
  if (tid==0){
    int run=0;
    for(int i=0;i<256;i++){ int t=part[i]; part[i]=run; run+=t; }
  }
  __syncthreads();
  int run = part[tid];
  for (int k=0;k<CH;k++){
    int n=base+k;
    if (n<NNODES){
      int di = deg_in[n];
      row_off[n]=run; cursor[n]=run;
      run += (di+7)&~7;
      norm_d[n] = rsqrtf(fmaxf((float)di,1.0f));
      norm_s[n] = rsqrtf(fmaxf((float)deg_out[n],1.0f));
    }
  }
  if (tid==255) row_off[NNODES]=run;   // padded E
}

// csr entry = src node only (norm_s is folded into the stored y = hW values)
__global__ void fill_kernel(const int* __restrict__ src, const int* __restrict__ dst,
                            int* __restrict__ cursor, int* __restrict__ csr, int E){
  int e = blockIdx.x*blockDim.x + threadIdx.x;
  if (e<E){
    int pos = atomicAdd(&cursor[dst[e]],1);
    csr[pos] = src[e];
  }
}

// fill pad slots with sentinel node NNODES (its y-row is permanently zero)
__global__ void pad_kernel(const int* __restrict__ row_off, const int* __restrict__ cursor,
                           int* __restrict__ csr){
  int n = blockIdx.x*blockDim.x + threadIdx.x;
  if (n < NNODES){
    int q  = cursor[n];        // row_off[n] + deg_in[n] after fill_kernel
    int qe = row_off[n+1];
    for (; q < qe; ++q) csr[q] = NNODES;
  }
}

__global__ void xproj_kernel(const float* __restrict__ x,
                             const float* __restrict__ wr, const float* __restrict__ br,
                             const float* __restrict__ wz, const float* __restrict__ bz,
                             const float* __restrict__ wh, const float* __restrict__ bh,
                             float* __restrict__ xproj){
  int tid = threadIdx.x;             // 0..383
  if (tid >= 384) return;
  int g = tid >> 7; int r = tid & 127; int b = r >> 6; int i = r & 63;
  const float* w  = (g==0)?wr:(g==1)?wz:wh;
  const float* bb = (g==0)?br:(g==1)?bz:bh;
  float s = bb[i];
  for (int k=0;k<INDIM;k++) s = fmaf(x[b*INDIM+k], w[k*HDIM+i], s);
  xproj[g*128 + i*2 + b] = s;
}

__global__ void transpose_w_kernel(const float* __restrict__ gcn_w, float* __restrict__ wT){
  int tid = threadIdx.x;                  // 256 threads, 16 elems each
  for (int k=0;k<16;k++){
    int idx = tid*16 + k;                 // 0..4095
    int i = idx >> 6, j = idx & 63;       // wT[i][j] = W[j][i]
    wT[idx] = gcn_w[j*HDIM + i];
  }
}

// One wave per node, lane = H index. Gathers SUM pre-multiplied bf16 y = norm_s*(h@W)
// rows (sentinel row NNODES is zero). Then GRU gates, then this node's y_new = h_new@W
// via LDS-staged W (swizzled, VGPR-cheap) for the next step.
__launch_bounds__(512, 6)
__global__ void step_kernel(const float2* __restrict__ h_in, float2* __restrict__ h_out,
                            const uint32_t* __restrict__ yb_in, uint32_t* __restrict__ yb_out,
                            float* __restrict__ out, int t,
                            const int* __restrict__ row_off, const int* __restrict__ csr,
                            const float* __restrict__ norm_d, const float* __restrict__ norm_s,
                            const float* __restrict__ wT, const float* __restrict__ gcn_b,
                            const float2* __restrict__ xproj){
  __shared__ __align__(16) float4 wlds[64][16];     // 16 KB: wlds[l][k^sl(l)] = W[4k..4k+3][l]
  __shared__ __align__(16) float2 hstage[8][64];    // 4 KB, wave-private rows

  const int tid  = threadIdx.x;
  const int lane = tid & 63;
  const int wv   = tid >> 6;                        // 0..7

  // stage W into LDS, swizzled at float4 granularity (bank-quad balanced reads)
  {
    const float4* wt4 = (const float4*)wT;          // 1024 chunks
    #pragma unroll
    for (int q=0;q<2;q++){
      int c = tid*2 + q;                            // 0..1023
      int l = c >> 4, k = c & 15;
      int sl = (l & 15) ^ (((l>>4)&1) << 2);
      wlds[l][k ^ sl] = wt4[c];
    }
  }

  const int n   = __builtin_amdgcn_readfirstlane(blockIdx.x*8 + wv);  // 0..9999
  const int beg = __builtin_amdgcn_readfirstlane(row_off[n]);
  const int end = __builtin_amdgcn_readfirstlane(row_off[n+1]);

  __syncthreads();   // wlds ready

  float2 hold = h_in[(size_t)n*HDIM + lane];   // fp32 state

  // gather-sum: rows padded to 8, sentinel rows are zero -> branch-free.
  // 32-bit offsets (SGPR base + voffset) keep address VGPR pressure low.
  const uint32_t lane_u = (uint32_t)lane;
  float2 a0{0.f,0.f}, a1{0.f,0.f}, a2{0.f,0.f}, a3{0.f,0.f};
  const int4* cp = (const int4*)(csr + beg);   // beg % 8 == 0 -> 16B aligned
  int nIt = (end - beg) >> 3;
  #pragma unroll 1
  for (int it=0; it<nIt; ++it){
    int4 ca = cp[2*it];
    int4 cb = cp[2*it+1];
    uint32_t p0 = yb_in[(uint32_t)ca.x*HDIM + lane_u];
    uint32_t p1 = yb_in[(uint32_t)ca.y*HDIM + lane_u];
    uint32_t p2 = yb_in[(uint32_t)ca.z*HDIM + lane_u];
    uint32_t p3 = yb_in[(uint32_t)ca.w*HDIM + lane_u];
    uint32_t p4 = yb_in[(uint32_t)cb.x*HDIM + lane_u];
    uint32_t p5 = yb_in[(uint32_t)cb.y*HDIM + lane_u];
    uint32_t p6 = yb_in[(uint32_t)cb.z*HDIM + lane_u];
    uint32_t p7 = yb_in[(uint32_t)cb.w*HDIM + lane_u];
    a0.x += __uint_as_float(p0<<16); a0.y += __uint_as_float(p0 & 0xffff0000u);
    a1.x += __uint_as_float(p1<<16); a1.y += __uint_as_float(p1 & 0xffff0000u);
    a2.x += __uint_as_float(p2<<16); a2.y += __uint_as_float(p2 & 0xffff0000u);
    a3.x += __uint_as_float(p3<<16); a3.y += __uint_as_float(p3 & 0xffff0000u);
    a0.x += __uint_as_float(p4<<16); a0.y += __uint_as_float(p4 & 0xffff0000u);
    a1.x += __uint_as_float(p5<<16); a1.y += __uint_as_float(p5 & 0xffff0000u);
    a2.x += __uint_as_float(p6<<16); a2.y += __uint_as_float(p6 & 0xffff0000u);
    a3.x += __uint_as_float(p7<<16); a3.y += __uint_as_float(p7 & 0xffff0000u);
  }
  float s0 = (a0.x + a1.x) + (a2.x + a3.x);
  float s1 = (a0.y + a1.y) + (a2.y + a3.y);

  const float nd   = norm_d[n];
  const float ns   = norm_s[n];
  const float bias = gcn_b[lane];
  const float2 xrv = xproj[lane];
  const float2 xzv = xproj[64+lane];
  const float2 xhv = xproj[128+lane];

  float g0 = fmaf(nd, s0, bias);
  float g1 = fmaf(nd, s1, bias);

  float r0 = sigmoidf_(xrv.x + g0), r1 = sigmoidf_(xrv.y + g1);
  float z0 = sigmoidf_(xzv.x + g0), z1 = sigmoidf_(xzv.y + g1);
  float t0 = tanhf_(xhv.x + r0*g0), t1 = tanhf_(xhv.y + r1*g1);
  float hn0 = hold.x + z0*(t0 - hold.x);
  float hn1 = hold.y + z1*(t1 - hold.y);

  // global stores overlap with the matmul below
  const size_t NH = (size_t)NNODES*HDIM;
  h_out[(size_t)n*HDIM + lane] = make_float2(hn0,hn1);
  size_t idx = (size_t)t*NH + (size_t)n*HDIM + lane;
  __builtin_nontemporal_store(hn0, &out[idx]);                      // b=0 plane
  __builtin_nontemporal_store(hn1, &out[(size_t)TSTEPS*NH + idx]);  // b=1 plane

  // y_new = h_new @ W  (wave-local: hstage broadcast + per-lane W column from LDS)
  hstage[wv][lane] = make_float2(hn0,hn1);
  __asm__ volatile("s_waitcnt lgkmcnt(0)" ::: "memory");  // wave-private slot, DS in-order

  const int sl = (lane & 15) ^ (((lane>>4)&1) << 2);
  const float4* hp = (const float4*)hstage[wv];
  float y0 = 0.f, y1 = 0.f;
  #pragma unroll
  for (int k=0;k<16;k++){
    float4 w4 = wlds[lane][k ^ sl];   // W[4k+c][lane]
    float4 ha = hp[2*k];              // h[4k], h[4k+1]  (uniform addr: broadcast)
    float4 hb = hp[2*k+1];            // h[4k+2], h[4k+3]
    y0 = fmaf(w4.x, ha.x, y0); y1 = fmaf(w4.x, ha.y, y1);
    y0 = fmaf(w4.y, ha.z, y0); y1 = fmaf(w4.y, ha.w, y1);
    y0 = fmaf(w4.z, hb.x, y0); y1 = fmaf(w4.z, hb.y, y1);
    y0 = fmaf(w4.w, hb.z, y0); y1 = fmaf(w4.w, hb.w, y1);
  }
  yb_out[(size_t)n*HDIM + lane] = pack_bf16x2(ns*y0, ns*y1);
}

extern "C" void kernel_launch(void* const* d_in, const int* in_sizes, int n_in,
                              void* d_out, int out_size, void* d_ws, size_t ws_size,
                              hipStream_t stream){
  const float* x   = (const float*)d_in[0];
  const int*   src = (const int*)d_in[1];
  const int*   dst = (const int*)d_in[2];
  const float* wr  = (const float*)d_in[3];
  const float* br  = (const float*)d_in[4];
  const float* wz  = (const float*)d_in[5];
  const float* bz  = (const float*)d_in[6];
  const float* wh  = (const float*)d_in[7];
  const float* bh  = (const float*)d_in[8];
  const float* gw  = (const float*)d_in[9];
  const float* gb  = (const float*)d_in[10];
  float* out = (float*)d_out;
  const int E = in_sizes[1];

  char* ws = (char*)d_ws;
  size_t o = 0;
  int*   deg_out = (int*)(ws+o);  o += 10240*4;
  int*   deg_in  = (int*)(ws+o);  o += 10240*4;
  int*   cursor  = (int*)(ws+o);  o += 10240*4;
  int*   row_off = (int*)(ws+o);  o += 10256*4;
  float* norm_s  = (float*)(ws+o); o += 10240*4;
  float* norm_d  = (float*)(ws+o); o += 10240*4;
  const size_t CSRCAP = (size_t)E + 7*NNODES + 16;   // padded rows
  int*   csr     = (int*)(ws+o);  o += ((CSRCAP*4 + 15) & ~(size_t)15);
  float* xproj   = (float*)(ws+o); o += 512*4;
  float* wT      = (float*)(ws+o); o += 4096*4;
  o = (o + 255) & ~(size_t)255;
  const size_t NHf2 = (size_t)NNODES*HDIM*sizeof(float2);        // 5.12 MB
  const size_t NYB  = (size_t)(NNODES+1)*HDIM*sizeof(uint32_t);  // 2.56 MB (+sentinel row)
  float2*   h0  = (float2*)(ws+o);   o += NHf2;
  uint32_t* yb0 = (uint32_t*)(ws+o); o += NYB;   // contiguous with h0 -> one memset
  uint32_t* yb1 = (uint32_t*)(ws+o); o += NYB;   // sentinel row must be zero too
  float2*   h1  = (float2*)(ws+o);   o += NHf2;  // fully written before first read

  hipMemsetAsync(deg_out, 0, 2*10240*4, stream);
  hipMemsetAsync(h0, 0, NHf2 + 2*NYB, stream);   // zeros h0, yb0, yb1

  int eb = (E+255)/256;
  hist_kernel<<<eb,256,0,stream>>>(src,dst,deg_out,deg_in,E);
  scan_kernel<<<1,256,0,stream>>>(deg_in,deg_out,row_off,cursor,norm_s,norm_d);
  fill_kernel<<<eb,256,0,stream>>>(src,dst,cursor,csr,E);
  pad_kernel<<<(NNODES+255)/256,256,0,stream>>>(row_off,cursor,csr);
  xproj_kernel<<<1,384,0,stream>>>(x,wr,br,wz,bz,wh,bh,xproj);
  transpose_w_kernel<<<1,256,0,stream>>>(gw,wT);

  float2* hin = h0;  float2* hout = h1;
  uint32_t* ybin = yb0; uint32_t* ybout = yb1;
  for (int t=0;t<TSTEPS;t++){
    step_kernel<<<1250,512,0,stream>>>(hin,hout,ybin,ybout,out,t,row_off,csr,
                                       norm_d,norm_s,wT,gb,(const float2*)xproj);
    float2* tf = hin; hin = hout; hout = tf;
    uint32_t* tb = ybin; ybin = ybout; ybout = tb;
  }
}